// Round 6
// baseline (267.992 us; speedup 1.0000x reference)
//
#include <hip/hip_runtime.h>
#include <hip/hip_bf16.h>
#include <float.h>

#define N_SAMP   1024
#define C_IN     22
#define HW       361
#define C_TRUNK  384
#define HID      128
#define NHIST    5
#define HIST_START 9
#define NGATE    512   // 4*HID

typedef __attribute__((ext_vector_type(8))) short short8v;
typedef __attribute__((ext_vector_type(4))) float float4v;

static __device__ __forceinline__ ushort f2bf(float x) {
  unsigned int b = __float_as_uint(x);
  b += 0x7fffu + ((b >> 16) & 1u);
  return (ushort)(b >> 16);
}

// ---------------- Kernel A: argmax + movement flag + w_ih -> bf16 ------------
// 1024 blocks x 320 threads. Wave t reduces history plane t (shuffle
// butterfly). Blocks 0..767 additionally convert 256 elements of w_ih to bf16
// (196608 total), overlapped/free.
__global__ __launch_bounds__(320) void argmax_kernel(
    const float* __restrict__ inp,   // (N, 22, 361)
    const float* __restrict__ w_ih,  // (512, 384)
    int*    __restrict__ idxb,       // (N, 5)
    float*  __restrict__ movb,       // (N, 5)
    ushort* __restrict__ w_ihb)      // (512, 384) bf16
{
  const int n    = blockIdx.x;
  const int tid  = threadIdx.x;
  const int wave = tid >> 6;   // 0..4
  const int lane = tid & 63;

  if (n < 768 && tid < 256) {
    int o = n * 256 + tid;
    w_ihb[o] = f2bf(w_ih[o]);
  }

  const float* base = inp + ((size_t)n * C_IN + HIST_START + wave) * HW;
  float v = -FLT_MAX; int vi = 0; float sum = 0.f;
  #pragma unroll
  for (int r = 0; r < 6; ++r) {
    int i = lane + r * 64;
    if (i < HW) {
      float x = base[i];
      sum += x;
      if (x > v) { v = x; vi = i; }   // strict > keeps first occurrence
    }
  }
  #pragma unroll
  for (int m = 1; m < 64; m <<= 1) {
    float v2 = __shfl_xor(v, m);
    int   i2 = __shfl_xor(vi, m);
    float s2 = __shfl_xor(sum, m);
    if (v2 > v || (v2 == v && i2 < vi)) { v = v2; vi = i2; }  // min idx on tie
    sum += s2;
  }
  if (lane == 0) {
    idxb[n * NHIST + wave] = vi;
    movb[n * NHIST + wave] = (sum > 0.5f) ? 1.f : 0.f;
  }
}

// ---------------- Kernel B: fused gather + gates GEMM (bf16 MFMA) ------------
// G[r][j] = mov_r * (trunk[n_r, :, p_r] . w_ih[j,:]) + b_ih[j] + b_hh[j],
// where r = n*5 + t and (p_r, mov_r) come from history step 4-t (reversal).
// Grid (8 j-tiles x 80 m-tiles), 256 thr. A-tile staged straight from trunk
// via 8 scattered dword loads/thread/k-step, register-prefetched 1 step ahead.
// j is the fastest grid dim -> the 8 sibling blocks sharing an m-tile are
// dispatch-adjacent -> gather lines hit L2 after the first sibling.
__global__ __launch_bounds__(256) void gates_kernel(
    const float*  __restrict__ trunk,  // (N, 384, 361)
    const ushort* __restrict__ w_ihb,  // (512, 384) bf16
    const int*    __restrict__ idxb,   // (N, 5)
    const float*  __restrict__ movb,   // (N, 5)
    const float*  __restrict__ b_ih,   // (512)
    const float*  __restrict__ b_hh,   // (512)
    float* __restrict__ G)             // (5120, 512)
{
  __shared__ ushort As[64][40];   // 64 rows x 32 k (+8 pad)
  __shared__ ushort Bs[64][40];
  const int tid  = threadIdx.x;
  const int wv   = tid >> 6;
  const int lane = tid & 63;
  const int m0 = blockIdx.y * 64;
  const int j0 = blockIdx.x * 64;
  const int row_l = tid >> 2;          // 0..63: (n,t) row this thread stages
  const int koff  = (tid & 3) * 8;     // k offset {0,8,16,24}

  // per-row gather parameters (fixed across k-loop)
  const int r  = m0 + row_l;
  const int nn = r / 5;
  const int tt = r - nn * 5;
  const int   ip = idxb[nn * NHIST + 4 - tt];   // reversal
  const float mr = movb[nn * NHIST + 4 - tt];

  float4v acc0 = {0.f,0.f,0.f,0.f};
  float4v acc1 = {0.f,0.f,0.f,0.f};
  float4v acc2 = {0.f,0.f,0.f,0.f};
  float4v acc3 = {0.f,0.f,0.f,0.f};

  const int fr = lane & 15;
  const int fk = (lane >> 4) * 8;

  // scattered A prefetch registers (k-step pipelined)
  float va[8];
  {
    const float* tp = trunk + ((size_t)nn * C_TRUNK + koff) * HW + ip;
    #pragma unroll
    for (int q = 0; q < 8; ++q) va[q] = tp[q * HW];
  }

  for (int k0 = 0; k0 < C_TRUNK; k0 += 32) {
    // write prefetched A values (masked, cvt to bf16) + stage B tile
    short8v avec;
    #pragma unroll
    for (int q = 0; q < 8; ++q) avec[q] = (short)f2bf(va[q] * mr);
    *(short8v*)&As[row_l][koff] = avec;
    *(short8v*)&Bs[row_l][koff] =
        *(const short8v*)(w_ihb + (size_t)(j0 + row_l) * C_TRUNK + k0 + koff);
    __syncthreads();

    // issue next k-step's scattered loads (latency hidden under MFMA phase)
    if (k0 + 32 < C_TRUNK) {
      const float* tp = trunk + ((size_t)nn * C_TRUNK + k0 + 32 + koff) * HW + ip;
      #pragma unroll
      for (int q = 0; q < 8; ++q) va[q] = tp[q * HW];
    }

    short8v af  = *(const short8v*)&As[wv * 16 + fr][fk];
    short8v bf0 = *(const short8v*)&Bs[ 0 + fr][fk];
    short8v bf1 = *(const short8v*)&Bs[16 + fr][fk];
    short8v bf2 = *(const short8v*)&Bs[32 + fr][fk];
    short8v bf3 = *(const short8v*)&Bs[48 + fr][fk];
    acc0 = __builtin_amdgcn_mfma_f32_16x16x32_bf16(af, bf0, acc0, 0, 0, 0);
    acc1 = __builtin_amdgcn_mfma_f32_16x16x32_bf16(af, bf1, acc1, 0, 0, 0);
    acc2 = __builtin_amdgcn_mfma_f32_16x16x32_bf16(af, bf2, acc2, 0, 0, 0);
    acc3 = __builtin_amdgcn_mfma_f32_16x16x32_bf16(af, bf3, acc3, 0, 0, 0);
    __syncthreads();
  }

  const int rbase = m0 + wv * 16 + (lane >> 4) * 4;
  #pragma unroll
  for (int j = 0; j < 4; ++j) {
    const float4v a = (j == 0) ? acc0 : (j == 1) ? acc1 : (j == 2) ? acc2 : acc3;
    const int cj = j0 + j * 16 + fr;
    const float bsum = b_ih[cj] + b_hh[cj];
    #pragma unroll
    for (int rr = 0; rr < 4; ++rr)
      G[(size_t)(rbase + rr) * NGATE + cj] = a[rr] + bsum;
  }
}

// ---------------- Kernel C: recurrence + projection (unchanged) --------------
__global__ __launch_bounds__(512, 2) void lstm_kernel(
    const float* __restrict__ G,       // (1024, 5, 512)
    const float* __restrict__ w_hh,    // (512, 128)
    const float* __restrict__ w_proj,  // (384, 128)
    const float* __restrict__ b_proj,  // (384)
    float* __restrict__ out)           // (1024, 384)
{
  const int n0  = blockIdx.x * 4;
  const int tid = threadIdx.x;
  const int g   = tid >> 7;
  const int j   = tid & 127;

  __shared__ float hs[4][HID];
  __shared__ float glds[4][4][HID];

  float gpre[NHIST][4];
  #pragma unroll
  for (int t = 0; t < NHIST; ++t)
    #pragma unroll
    for (int s = 0; s < 4; ++s)
      gpre[t][s] = G[((size_t)(n0 + s) * NHIST + t) * NGATE + tid];

  float4 wreg[32];
  #pragma unroll
  for (int k4 = 0; k4 < 32; ++k4)
    wreg[k4] = *(const float4*)(w_hh + (size_t)(g * HID + j) * HID + k4 * 4);

  hs[g][j] = 0.f;
  float c = 0.f;
  __syncthreads();

  #pragma unroll
  for (int t = 0; t < NHIST; ++t) {
    float a[4];
    #pragma unroll
    for (int s = 0; s < 4; ++s) a[s] = gpre[t][s];

    #pragma unroll
    for (int k4 = 0; k4 < 32; ++k4) {
      float4 w = wreg[k4];
      #pragma unroll
      for (int s = 0; s < 4; ++s) {
        float4 h = *(const float4*)&hs[s][k4 * 4];
        a[s] += w.x * h.x + w.y * h.y + w.z * h.z + w.w * h.w;
      }
    }
    #pragma unroll
    for (int s = 0; s < 4; ++s) glds[g][s][j] = a[s];
    __syncthreads();
    {
      float ig = glds[0][g][j];
      float fg = glds[1][g][j];
      float gg = glds[2][g][j];
      float og = glds[3][g][j];
      ig = 1.f / (1.f + __expf(-ig));
      fg = 1.f / (1.f + __expf(-fg));
      og = 1.f / (1.f + __expf(-og));
      c  = fg * c + ig * tanhf(gg);
      hs[g][j] = og * tanhf(c);
    }
    __syncthreads();
  }

  if (tid < C_TRUNK) {
    const int cc = tid;
    const float4* wp = (const float4*)(w_proj + (size_t)cc * HID);
    float b = b_proj[cc];
    float po[4] = {b, b, b, b};
    #pragma unroll 8
    for (int k4 = 0; k4 < 32; ++k4) {
      float4 w  = wp[k4];
      float4 h0 = *(const float4*)&hs[0][k4 * 4];
      float4 h1 = *(const float4*)&hs[1][k4 * 4];
      float4 h2 = *(const float4*)&hs[2][k4 * 4];
      float4 h3 = *(const float4*)&hs[3][k4 * 4];
      po[0] += w.x*h0.x + w.y*h0.y + w.z*h0.z + w.w*h0.w;
      po[1] += w.x*h1.x + w.y*h1.y + w.z*h1.z + w.w*h1.w;
      po[2] += w.x*h2.x + w.y*h2.y + w.z*h2.z + w.w*h2.w;
      po[3] += w.x*h3.x + w.y*h3.y + w.z*h3.z + w.w*h3.w;
    }
    #pragma unroll
    for (int s = 0; s < 4; ++s)
      out[(size_t)(n0 + s) * C_TRUNK + cc] = po[s];
  }
}

extern "C" void kernel_launch(void* const* d_in, const int* in_sizes, int n_in,
                              void* d_out, int out_size, void* d_ws, size_t ws_size,
                              hipStream_t stream) {
  const float* inp    = (const float*)d_in[0];
  const float* trunk  = (const float*)d_in[1];
  const float* w_ih   = (const float*)d_in[2];
  const float* w_hh   = (const float*)d_in[3];
  const float* b_ih   = (const float*)d_in[4];
  const float* b_hh   = (const float*)d_in[5];
  const float* w_proj = (const float*)d_in[6];
  const float* b_proj = (const float*)d_in[7];
  float* out = (float*)d_out;

  char* ws = (char*)d_ws;
  int*    idxb  = (int*)ws;                      // 1024*5 int   (pad to 20480)
  float*  movb  = (float*)(ws + 20480);          // 1024*5 f32   (pad to 20480)
  ushort* w_ihb = (ushort*)(ws + 40960);         // 512*384 bf16 (393216 B)
  float*  G     = (float*)(ws + 40960 + 393216); // 5120*512 f32

  argmax_kernel<<<N_SAMP, 320, 0, stream>>>(inp, w_ih, idxb, movb, w_ihb);
  gates_kernel<<<dim3(NGATE / 64, (N_SAMP * NHIST) / 64), 256, 0, stream>>>(
      trunk, w_ihb, idxb, movb, b_ih, b_hh, G);
  lstm_kernel<<<N_SAMP / 4, 512, 0, stream>>>(G, w_hh, w_proj, b_proj, out);
}

// Round 7
// 81.214 us; speedup vs baseline: 3.2998x; 3.2998x over previous
//
#include <hip/hip_runtime.h>
#include <hip/hip_bf16.h>
#include <float.h>

#define N_SAMP   1024
#define C_IN     22
#define HW       361
#define C_TRUNK  384
#define HID      128
#define NHIST    5
#define HIST_START 9
#define NGATE    512   // 4*HID

typedef __attribute__((ext_vector_type(8))) short short8v;
typedef __attribute__((ext_vector_type(4))) float float4v;

static __device__ __forceinline__ ushort f2bf(float x) {
  unsigned int b = __float_as_uint(x);
  b += 0x7fffu + ((b >> 16) & 1u);
  return (ushort)(b >> 16);
}

// ---------------- Kernel A: argmax + movement flag + w_ih -> bf16 ------------
// 1024 blocks x 320 threads. Wave t reduces history plane t (shuffle
// butterfly). Blocks 0..767 also convert 256 elements of w_ih to bf16 (free).
__global__ __launch_bounds__(320) void argmax_kernel(
    const float* __restrict__ inp,   // (N, 22, 361)
    const float* __restrict__ w_ih,  // (512, 384)
    int*    __restrict__ idxb,       // (N, 5)
    float*  __restrict__ movb,       // (N, 5)
    ushort* __restrict__ w_ihb)      // (512, 384) bf16
{
  const int n    = blockIdx.x;
  const int tid  = threadIdx.x;
  const int wave = tid >> 6;   // 0..4
  const int lane = tid & 63;

  if (n < 768 && tid < 256) {
    int o = n * 256 + tid;
    w_ihb[o] = f2bf(w_ih[o]);
  }

  const float* base = inp + ((size_t)n * C_IN + HIST_START + wave) * HW;
  float v = -FLT_MAX; int vi = 0; float sum = 0.f;
  #pragma unroll
  for (int r = 0; r < 6; ++r) {
    int i = lane + r * 64;
    if (i < HW) {
      float x = base[i];
      sum += x;
      if (x > v) { v = x; vi = i; }   // strict > keeps first occurrence
    }
  }
  #pragma unroll
  for (int m = 1; m < 64; m <<= 1) {
    float v2 = __shfl_xor(v, m);
    int   i2 = __shfl_xor(vi, m);
    float s2 = __shfl_xor(sum, m);
    if (v2 > v || (v2 == v && i2 < vi)) { v = v2; vi = i2; }  // min idx on tie
    sum += s2;
  }
  if (lane == 0) {
    idxb[n * NHIST + wave] = vi;
    movb[n * NHIST + wave] = (sum > 0.5f) ? 1.f : 0.f;
  }
}

// ---------------- Kernel B: gather (reversal + masking), pure scatter --------
// 1024 blocks x 192 threads; thread handles rows c and c+192 -> 10 scattered
// loads in flight per thread (same 1444B trunk rows -> DRAM page locality).
__global__ __launch_bounds__(192) void gather_kernel(
    const float* __restrict__ trunk,  // (N, 384, 361)
    const int*   __restrict__ idxb,   // (N, 5)
    const float* __restrict__ movb,   // (N, 5)
    ushort* __restrict__ seq)         // (N, 5, 384) bf16, reversed + masked
{
  const int n = blockIdx.x;
  const int c = threadIdx.x;           // 0..191; also handles c+192

  const int   i0 = idxb[n * NHIST + 4], i1 = idxb[n * NHIST + 3],
              i2 = idxb[n * NHIST + 2], i3 = idxb[n * NHIST + 1],
              i4 = idxb[n * NHIST + 0];
  const float m0 = movb[n * NHIST + 4], m1 = movb[n * NHIST + 3],
              m2 = movb[n * NHIST + 2], m3 = movb[n * NHIST + 1],
              m4 = movb[n * NHIST + 0];

  const float* ta = trunk + ((size_t)n * C_TRUNK + c) * HW;
  const float* tb = ta + (size_t)192 * HW;
  float a0 = ta[i0], a1 = ta[i1], a2 = ta[i2], a3 = ta[i3], a4 = ta[i4];
  float b0 = tb[i0], b1 = tb[i1], b2 = tb[i2], b3 = tb[i3], b4 = tb[i4];

  ushort* so = seq + (size_t)n * NHIST * C_TRUNK + c;
  so[0 * C_TRUNK]       = f2bf(a0 * m0);   // seq[t] = feats[4-t]
  so[1 * C_TRUNK]       = f2bf(a1 * m1);
  so[2 * C_TRUNK]       = f2bf(a2 * m2);
  so[3 * C_TRUNK]       = f2bf(a3 * m3);
  so[4 * C_TRUNK]       = f2bf(a4 * m4);
  so[0 * C_TRUNK + 192] = f2bf(b0 * m0);
  so[1 * C_TRUNK + 192] = f2bf(b1 * m1);
  so[2 * C_TRUNK + 192] = f2bf(b2 * m2);
  so[3 * C_TRUNK + 192] = f2bf(b3 * m3);
  so[4 * C_TRUNK + 192] = f2bf(b4 * m4);
}

// ---------------- Kernel C: G = seq @ w_ih^T + b_ih + b_hh  (bf16 MFMA) ------
// M=5120, N=512, K=384. BM=BN=64, BK=32, 256 threads = 4 waves. B from
// pre-converted bf16 w_ihb (no cvt in staging path).
__global__ __launch_bounds__(256) void gates_kernel(
    const ushort* __restrict__ seq,    // (5120, 384) bf16
    const ushort* __restrict__ w_ihb,  // (512, 384) bf16
    const float*  __restrict__ b_ih,   // (512)
    const float*  __restrict__ b_hh,   // (512)
    float* __restrict__ G)             // (5120, 512)
{
  __shared__ ushort As[64][40];
  __shared__ ushort Bs[64][40];
  const int tid  = threadIdx.x;
  const int wv   = tid >> 6;
  const int lane = tid & 63;
  const int m0 = blockIdx.y * 64;
  const int j0 = blockIdx.x * 64;
  const int row_l = tid >> 2;
  const int koff  = (tid & 3) * 8;

  float4v acc0 = {0.f,0.f,0.f,0.f};
  float4v acc1 = {0.f,0.f,0.f,0.f};
  float4v acc2 = {0.f,0.f,0.f,0.f};
  float4v acc3 = {0.f,0.f,0.f,0.f};

  const int fr = lane & 15;
  const int fk = (lane >> 4) * 8;

  for (int k0 = 0; k0 < C_TRUNK; k0 += 32) {
    *(short8v*)&As[row_l][koff] =
        *(const short8v*)(seq + (size_t)(m0 + row_l) * C_TRUNK + k0 + koff);
    *(short8v*)&Bs[row_l][koff] =
        *(const short8v*)(w_ihb + (size_t)(j0 + row_l) * C_TRUNK + k0 + koff);
    __syncthreads();

    short8v af  = *(const short8v*)&As[wv * 16 + fr][fk];
    short8v bf0 = *(const short8v*)&Bs[ 0 + fr][fk];
    short8v bf1 = *(const short8v*)&Bs[16 + fr][fk];
    short8v bf2 = *(const short8v*)&Bs[32 + fr][fk];
    short8v bf3 = *(const short8v*)&Bs[48 + fr][fk];
    acc0 = __builtin_amdgcn_mfma_f32_16x16x32_bf16(af, bf0, acc0, 0, 0, 0);
    acc1 = __builtin_amdgcn_mfma_f32_16x16x32_bf16(af, bf1, acc1, 0, 0, 0);
    acc2 = __builtin_amdgcn_mfma_f32_16x16x32_bf16(af, bf2, acc2, 0, 0, 0);
    acc3 = __builtin_amdgcn_mfma_f32_16x16x32_bf16(af, bf3, acc3, 0, 0, 0);
    __syncthreads();
  }

  const int rbase = m0 + wv * 16 + (lane >> 4) * 4;
  #pragma unroll
  for (int j = 0; j < 4; ++j) {
    const float4v a = (j == 0) ? acc0 : (j == 1) ? acc1 : (j == 2) ? acc2 : acc3;
    const int cj = j0 + j * 16 + fr;
    const float bsum = b_ih[cj] + b_hh[cj];
    #pragma unroll
    for (int r = 0; r < 4; ++r)
      G[(size_t)(rbase + r) * NGATE + cj] = a[r] + bsum;
  }
}

// ---------------- Kernel D: recurrence + projection (G fully prefetched) -----
__global__ __launch_bounds__(512, 2) void lstm_kernel(
    const float* __restrict__ G,       // (1024, 5, 512)
    const float* __restrict__ w_hh,    // (512, 128)
    const float* __restrict__ w_proj,  // (384, 128)
    const float* __restrict__ b_proj,  // (384)
    float* __restrict__ out)           // (1024, 384)
{
  const int n0  = blockIdx.x * 4;
  const int tid = threadIdx.x;
  const int g   = tid >> 7;
  const int j   = tid & 127;

  __shared__ float hs[4][HID];
  __shared__ float glds[4][4][HID];

  float gpre[NHIST][4];
  #pragma unroll
  for (int t = 0; t < NHIST; ++t)
    #pragma unroll
    for (int s = 0; s < 4; ++s)
      gpre[t][s] = G[((size_t)(n0 + s) * NHIST + t) * NGATE + tid];

  float4 wreg[32];
  #pragma unroll
  for (int k4 = 0; k4 < 32; ++k4)
    wreg[k4] = *(const float4*)(w_hh + (size_t)(g * HID + j) * HID + k4 * 4);

  hs[g][j] = 0.f;
  float c = 0.f;
  __syncthreads();

  #pragma unroll
  for (int t = 0; t < NHIST; ++t) {
    float a[4];
    #pragma unroll
    for (int s = 0; s < 4; ++s) a[s] = gpre[t][s];

    #pragma unroll
    for (int k4 = 0; k4 < 32; ++k4) {
      float4 w = wreg[k4];
      #pragma unroll
      for (int s = 0; s < 4; ++s) {
        float4 h = *(const float4*)&hs[s][k4 * 4];
        a[s] += w.x * h.x + w.y * h.y + w.z * h.z + w.w * h.w;
      }
    }
    #pragma unroll
    for (int s = 0; s < 4; ++s) glds[g][s][j] = a[s];
    __syncthreads();
    {
      float ig = glds[0][g][j];
      float fg = glds[1][g][j];
      float gg = glds[2][g][j];
      float og = glds[3][g][j];
      ig = 1.f / (1.f + __expf(-ig));
      fg = 1.f / (1.f + __expf(-fg));
      og = 1.f / (1.f + __expf(-og));
      c  = fg * c + ig * tanhf(gg);
      hs[g][j] = og * tanhf(c);
    }
    __syncthreads();
  }

  if (tid < C_TRUNK) {
    const int cc = tid;
    const float4* wp = (const float4*)(w_proj + (size_t)cc * HID);
    float b = b_proj[cc];
    float po[4] = {b, b, b, b};
    #pragma unroll 8
    for (int k4 = 0; k4 < 32; ++k4) {
      float4 w  = wp[k4];
      float4 h0 = *(const float4*)&hs[0][k4 * 4];
      float4 h1 = *(const float4*)&hs[1][k4 * 4];
      float4 h2 = *(const float4*)&hs[2][k4 * 4];
      float4 h3 = *(const float4*)&hs[3][k4 * 4];
      po[0] += w.x*h0.x + w.y*h0.y + w.z*h0.z + w.w*h0.w;
      po[1] += w.x*h1.x + w.y*h1.y + w.z*h1.z + w.w*h1.w;
      po[2] += w.x*h2.x + w.y*h2.y + w.z*h2.z + w.w*h2.w;
      po[3] += w.x*h3.x + w.y*h3.y + w.z*h3.z + w.w*h3.w;
    }
    #pragma unroll
    for (int s = 0; s < 4; ++s)
      out[(size_t)(n0 + s) * C_TRUNK + cc] = po[s];
  }
}

extern "C" void kernel_launch(void* const* d_in, const int* in_sizes, int n_in,
                              void* d_out, int out_size, void* d_ws, size_t ws_size,
                              hipStream_t stream) {
  const float* inp    = (const float*)d_in[0];
  const float* trunk  = (const float*)d_in[1];
  const float* w_ih   = (const float*)d_in[2];
  const float* w_hh   = (const float*)d_in[3];
  const float* b_ih   = (const float*)d_in[4];
  const float* b_hh   = (const float*)d_in[5];
  const float* w_proj = (const float*)d_in[6];
  const float* b_proj = (const float*)d_in[7];
  float* out = (float*)d_out;

  char* ws = (char*)d_ws;
  int*    idxb  = (int*)ws;                        // 1024*5 int  (pad 20480)
  float*  movb  = (float*)(ws + 20480);            // 1024*5 f32  (pad 20480)
  ushort* w_ihb = (ushort*)(ws + 40960);           // 512*384 bf16 (393216 B)
  ushort* seq   = (ushort*)(ws + 40960 + 393216);  // 5120*384 bf16
  float*  G     = (float*)(ws + 40960 + 393216 +
                   (size_t)N_SAMP * NHIST * C_TRUNK * sizeof(ushort));

  argmax_kernel<<<N_SAMP, 320, 0, stream>>>(inp, w_ih, idxb, movb, w_ihb);
  gather_kernel<<<N_SAMP, 192, 0, stream>>>(trunk, idxb, movb, seq);
  gates_kernel<<<dim3(NGATE / 64, (N_SAMP * NHIST) / 64), 256, 0, stream>>>(
      seq, w_ihb, b_ih, b_hh, G);
  lstm_kernel<<<N_SAMP / 4, 512, 0, stream>>>(G, w_hh, w_proj, b_proj, out);
}

// Round 8
// 77.874 us; speedup vs baseline: 3.4413x; 1.0429x over previous
//
#include <hip/hip_runtime.h>
#include <hip/hip_bf16.h>
#include <float.h>

#define N_SAMP   1024
#define C_IN     22
#define HW       361
#define C_TRUNK  384
#define HID      128
#define NHIST    5
#define HIST_START 9
#define NGATE    512   // 4*HID

typedef __attribute__((ext_vector_type(8))) short short8v;
typedef __attribute__((ext_vector_type(4))) float float4v;

static __device__ __forceinline__ ushort f2bf(float x) {
  unsigned int b = __float_as_uint(x);
  b += 0x7fffu + ((b >> 16) & 1u);
  return (ushort)(b >> 16);
}

// ---------------- Kernel A: argmax + movement flag + w_ih -> bf16 ------------
__global__ __launch_bounds__(320) void argmax_kernel(
    const float* __restrict__ inp,   // (N, 22, 361)
    const float* __restrict__ w_ih,  // (512, 384)
    int*    __restrict__ idxb,       // (N, 5)
    float*  __restrict__ movb,       // (N, 5)
    ushort* __restrict__ w_ihb)      // (512, 384) bf16
{
  const int n    = blockIdx.x;
  const int tid  = threadIdx.x;
  const int wave = tid >> 6;   // 0..4
  const int lane = tid & 63;

  if (n < 768 && tid < 256) {
    int o = n * 256 + tid;
    w_ihb[o] = f2bf(w_ih[o]);
  }

  const float* base = inp + ((size_t)n * C_IN + HIST_START + wave) * HW;
  float v = -FLT_MAX; int vi = 0; float sum = 0.f;
  #pragma unroll
  for (int r = 0; r < 6; ++r) {
    int i = lane + r * 64;
    if (i < HW) {
      float x = base[i];
      sum += x;
      if (x > v) { v = x; vi = i; }   // strict > keeps first occurrence
    }
  }
  #pragma unroll
  for (int m = 1; m < 64; m <<= 1) {
    float v2 = __shfl_xor(v, m);
    int   i2 = __shfl_xor(vi, m);
    float s2 = __shfl_xor(sum, m);
    if (v2 > v || (v2 == v && i2 < vi)) { v = v2; vi = i2; }  // min idx on tie
    sum += s2;
  }
  if (lane == 0) {
    idxb[n * NHIST + wave] = vi;
    movb[n * NHIST + wave] = (sum > 0.5f) ? 1.f : 0.f;
  }
}

// ---------------- Kernel B: gather (reversal + masking), pure scatter --------
__global__ __launch_bounds__(192) void gather_kernel(
    const float* __restrict__ trunk,  // (N, 384, 361)
    const int*   __restrict__ idxb,   // (N, 5)
    const float* __restrict__ movb,   // (N, 5)
    ushort* __restrict__ seq)         // (N, 5, 384) bf16, reversed + masked
{
  const int n = blockIdx.x;
  const int c = threadIdx.x;           // 0..191; also handles c+192

  const int   i0 = idxb[n * NHIST + 4], i1 = idxb[n * NHIST + 3],
              i2 = idxb[n * NHIST + 2], i3 = idxb[n * NHIST + 1],
              i4 = idxb[n * NHIST + 0];
  const float m0 = movb[n * NHIST + 4], m1 = movb[n * NHIST + 3],
              m2 = movb[n * NHIST + 2], m3 = movb[n * NHIST + 1],
              m4 = movb[n * NHIST + 0];

  const float* ta = trunk + ((size_t)n * C_TRUNK + c) * HW;
  const float* tb = ta + (size_t)192 * HW;
  float a0 = ta[i0], a1 = ta[i1], a2 = ta[i2], a3 = ta[i3], a4 = ta[i4];
  float b0 = tb[i0], b1 = tb[i1], b2 = tb[i2], b3 = tb[i3], b4 = tb[i4];

  ushort* so = seq + (size_t)n * NHIST * C_TRUNK + c;
  so[0 * C_TRUNK]       = f2bf(a0 * m0);   // seq[t] = feats[4-t]
  so[1 * C_TRUNK]       = f2bf(a1 * m1);
  so[2 * C_TRUNK]       = f2bf(a2 * m2);
  so[3 * C_TRUNK]       = f2bf(a3 * m3);
  so[4 * C_TRUNK]       = f2bf(a4 * m4);
  so[0 * C_TRUNK + 192] = f2bf(b0 * m0);
  so[1 * C_TRUNK + 192] = f2bf(b1 * m1);
  so[2 * C_TRUNK + 192] = f2bf(b2 * m2);
  so[3 * C_TRUNK + 192] = f2bf(b3 * m3);
  so[4 * C_TRUNK + 192] = f2bf(b4 * m4);
}

// ---------------- Kernel C: G = seq @ w_ih^T + b_ih + b_hh  (bf16 MFMA) ------
__global__ __launch_bounds__(256) void gates_kernel(
    const ushort* __restrict__ seq,    // (5120, 384) bf16
    const ushort* __restrict__ w_ihb,  // (512, 384) bf16
    const float*  __restrict__ b_ih,   // (512)
    const float*  __restrict__ b_hh,   // (512)
    float* __restrict__ G)             // (5120, 512)
{
  __shared__ ushort As[64][40];
  __shared__ ushort Bs[64][40];
  const int tid  = threadIdx.x;
  const int wv   = tid >> 6;
  const int lane = tid & 63;
  const int m0 = blockIdx.y * 64;
  const int j0 = blockIdx.x * 64;
  const int row_l = tid >> 2;
  const int koff  = (tid & 3) * 8;

  float4v acc0 = {0.f,0.f,0.f,0.f};
  float4v acc1 = {0.f,0.f,0.f,0.f};
  float4v acc2 = {0.f,0.f,0.f,0.f};
  float4v acc3 = {0.f,0.f,0.f,0.f};

  const int fr = lane & 15;
  const int fk = (lane >> 4) * 8;

  for (int k0 = 0; k0 < C_TRUNK; k0 += 32) {
    *(short8v*)&As[row_l][koff] =
        *(const short8v*)(seq + (size_t)(m0 + row_l) * C_TRUNK + k0 + koff);
    *(short8v*)&Bs[row_l][koff] =
        *(const short8v*)(w_ihb + (size_t)(j0 + row_l) * C_TRUNK + k0 + koff);
    __syncthreads();

    short8v af  = *(const short8v*)&As[wv * 16 + fr][fk];
    short8v bf0 = *(const short8v*)&Bs[ 0 + fr][fk];
    short8v bf1 = *(const short8v*)&Bs[16 + fr][fk];
    short8v bf2 = *(const short8v*)&Bs[32 + fr][fk];
    short8v bf3 = *(const short8v*)&Bs[48 + fr][fk];
    acc0 = __builtin_amdgcn_mfma_f32_16x16x32_bf16(af, bf0, acc0, 0, 0, 0);
    acc1 = __builtin_amdgcn_mfma_f32_16x16x32_bf16(af, bf1, acc1, 0, 0, 0);
    acc2 = __builtin_amdgcn_mfma_f32_16x16x32_bf16(af, bf2, acc2, 0, 0, 0);
    acc3 = __builtin_amdgcn_mfma_f32_16x16x32_bf16(af, bf3, acc3, 0, 0, 0);
    __syncthreads();
  }

  const int rbase = m0 + wv * 16 + (lane >> 4) * 4;
  #pragma unroll
  for (int j = 0; j < 4; ++j) {
    const float4v a = (j == 0) ? acc0 : (j == 1) ? acc1 : (j == 2) ? acc2 : acc3;
    const int cj = j0 + j * 16 + fr;
    const float bsum = b_ih[cj] + b_hh[cj];
    #pragma unroll
    for (int r = 0; r < 4; ++r)
      G[(size_t)(rbase + r) * NGATE + cj] = a[r] + bsum;
  }
}

// ---------------- Kernel D: recurrence + projection via MFMA -----------------
// 4 samples/block (grid=256=1 block/CU), 512 threads = 8 waves. Samples sit in
// rows 0-3 of the 16-row MFMA fragment (rows 4-15 zero). Wave w owns gate cols
// w*64..w*64+63 (4 frags x 4 k-steps, w_hh frags in regs). h carried bf16 in
// hswz[ks][lane][8]: A-frag reads are lane-contiguous conflict-free b128.
__global__ __launch_bounds__(512, 2) void lstm_kernel(
    const float* __restrict__ G,       // (5120, 512)
    const float* __restrict__ w_hh,    // (512, 128)
    const float* __restrict__ w_proj,  // (384, 128)
    const float* __restrict__ b_proj,  // (384)
    float* __restrict__ out)           // (1024, 384)
{
  const int n0   = blockIdx.x * 4;
  const int tid  = threadIdx.x;
  const int wv   = tid >> 6;       // 0..7
  const int lane = tid & 63;
  const int fr   = lane & 15;
  const int fq   = lane >> 4;      // 0..3

  __shared__ ushort hswz[4][64][8];   // [ks][lane][q]  4 KB
  __shared__ float  glds[NGATE][4];   // [gate col][sample]  8 KB

  // zero h0 (also zeroes fragment rows 4..15, which stay zero forever)
  ((ushort4*)hswz)[tid] = make_ushort4(0, 0, 0, 0);

  // recurrent B-fragments: w_hh, cols j0w..j0w+63, K=128 in 4 ks-steps
  const int j0w = wv * 64;
  short8v bfrag[4][4];                // [colfrag][ks]
  #pragma unroll
  for (int f = 0; f < 4; ++f)
    #pragma unroll
    for (int ks = 0; ks < 4; ++ks) {
      const float* wr = w_hh + (size_t)(j0w + f*16 + fr) * HID + ks*32 + fq*8;
      float4 lo = *(const float4*)wr;
      float4 hi = *(const float4*)(wr + 4);
      short8v b;
      b[0]=(short)f2bf(lo.x); b[1]=(short)f2bf(lo.y);
      b[2]=(short)f2bf(lo.z); b[3]=(short)f2bf(lo.w);
      b[4]=(short)f2bf(hi.x); b[5]=(short)f2bf(hi.y);
      b[6]=(short)f2bf(hi.z); b[7]=(short)f2bf(hi.w);
      bfrag[f][ks] = b;
    }

  // G prefetch as MFMA C-init: D row r = sample r lives in lanes fq==0, reg r
  float4v gpre[NHIST][4];
  #pragma unroll
  for (int t = 0; t < NHIST; ++t)
    #pragma unroll
    for (int f = 0; f < 4; ++f) {
      float4v v = {0.f, 0.f, 0.f, 0.f};
      if (fq == 0) {
        const int col = j0w + f*16 + fr;
        #pragma unroll
        for (int r = 0; r < 4; ++r)
          v[r] = G[((size_t)(n0 + r) * NHIST + t) * NGATE + col];
      }
      gpre[t][f] = v;
    }

  float c4[4] = {0.f, 0.f, 0.f, 0.f};   // threads 0..127: unit tid, samples 0-3
  __syncthreads();

  #pragma unroll
  for (int t = 0; t < NHIST; ++t) {
    // A-fragments of h_{t-1}: conflict-free lane-contiguous 16B reads
    short8v af0 = *(const short8v*)&hswz[0][lane][0];
    short8v af1 = *(const short8v*)&hswz[1][lane][0];
    short8v af2 = *(const short8v*)&hswz[2][lane][0];
    short8v af3 = *(const short8v*)&hswz[3][lane][0];
    #pragma unroll
    for (int f = 0; f < 4; ++f) {
      float4v acc = gpre[t][f];
      acc = __builtin_amdgcn_mfma_f32_16x16x32_bf16(af0, bfrag[f][0], acc, 0, 0, 0);
      acc = __builtin_amdgcn_mfma_f32_16x16x32_bf16(af1, bfrag[f][1], acc, 0, 0, 0);
      acc = __builtin_amdgcn_mfma_f32_16x16x32_bf16(af2, bfrag[f][2], acc, 0, 0, 0);
      acc = __builtin_amdgcn_mfma_f32_16x16x32_bf16(af3, bfrag[f][3], acc, 0, 0, 0);
      if (fq == 0)
        *(float4v*)&glds[j0w + f*16 + fr][0] = acc;   // 4 samples contiguous
    }
    __syncthreads();

    if (tid < HID) {          // threads 0..127: unit j, all 4 samples
      const int j = tid;
      float4 iv = *(const float4*)&glds[      j][0];
      float4 fv = *(const float4*)&glds[128 + j][0];
      float4 gv = *(const float4*)&glds[256 + j][0];
      float4 ov = *(const float4*)&glds[384 + j][0];
      float ia[4] = {iv.x, iv.y, iv.z, iv.w};
      float fa[4] = {fv.x, fv.y, fv.z, fv.w};
      float ga[4] = {gv.x, gv.y, gv.z, gv.w};
      float oa[4] = {ov.x, ov.y, ov.z, ov.w};
      #pragma unroll
      for (int s = 0; s < 4; ++s) {
        float ig = 1.f / (1.f + __expf(-ia[s]));
        float fg = 1.f / (1.f + __expf(-fa[s]));
        float og = 1.f / (1.f + __expf(-oa[s]));
        c4[s] = fg * c4[s] + ig * tanhf(ga[s]);
        float h = og * tanhf(c4[s]);
        // hswz[k=j]: ks=j>>5, lane'=((j>>3)&3)*16 + s, q=j&7
        hswz[j >> 5][((j >> 3) & 3) * 16 + s][j & 7] = f2bf(h);
      }
    }
    __syncthreads();
  }

  // projection: out[4 x 384] = h_final @ w_proj^T + b_proj, same MFMA scheme.
  // pfrag loaded after recurrence (gpre/bfrag dead -> no extra VGPR pressure).
  const int j0p = wv * 48;
  short8v pfrag[3][4];
  #pragma unroll
  for (int f = 0; f < 3; ++f)
    #pragma unroll
    for (int ks = 0; ks < 4; ++ks) {
      const float* wr = w_proj + (size_t)(j0p + f*16 + fr) * HID + ks*32 + fq*8;
      float4 lo = *(const float4*)wr;
      float4 hi = *(const float4*)(wr + 4);
      short8v b;
      b[0]=(short)f2bf(lo.x); b[1]=(short)f2bf(lo.y);
      b[2]=(short)f2bf(lo.z); b[3]=(short)f2bf(lo.w);
      b[4]=(short)f2bf(hi.x); b[5]=(short)f2bf(hi.y);
      b[6]=(short)f2bf(hi.z); b[7]=(short)f2bf(hi.w);
      pfrag[f][ks] = b;
    }

  short8v hf0 = *(const short8v*)&hswz[0][lane][0];
  short8v hf1 = *(const short8v*)&hswz[1][lane][0];
  short8v hf2 = *(const short8v*)&hswz[2][lane][0];
  short8v hf3 = *(const short8v*)&hswz[3][lane][0];
  #pragma unroll
  for (int f = 0; f < 3; ++f) {
    const int col = j0p + f * 16 + fr;
    const float bp = b_proj[col];
    float4v acc = {bp, bp, bp, bp};
    acc = __builtin_amdgcn_mfma_f32_16x16x32_bf16(hf0, pfrag[f][0], acc, 0, 0, 0);
    acc = __builtin_amdgcn_mfma_f32_16x16x32_bf16(hf1, pfrag[f][1], acc, 0, 0, 0);
    acc = __builtin_amdgcn_mfma_f32_16x16x32_bf16(hf2, pfrag[f][2], acc, 0, 0, 0);
    acc = __builtin_amdgcn_mfma_f32_16x16x32_bf16(hf3, pfrag[f][3], acc, 0, 0, 0);
    if (fq == 0) {
      #pragma unroll
      for (int r = 0; r < 4; ++r)
        out[(size_t)(n0 + r) * C_TRUNK + col] = acc[r];
    }
  }
}

extern "C" void kernel_launch(void* const* d_in, const int* in_sizes, int n_in,
                              void* d_out, int out_size, void* d_ws, size_t ws_size,
                              hipStream_t stream) {
  const float* inp    = (const float*)d_in[0];
  const float* trunk  = (const float*)d_in[1];
  const float* w_ih   = (const float*)d_in[2];
  const float* w_hh   = (const float*)d_in[3];
  const float* b_ih   = (const float*)d_in[4];
  const float* b_hh   = (const float*)d_in[5];
  const float* w_proj = (const float*)d_in[6];
  const float* b_proj = (const float*)d_in[7];
  float* out = (float*)d_out;

  char* ws = (char*)d_ws;
  int*    idxb  = (int*)ws;                        // 1024*5 int  (pad 20480)
  float*  movb  = (float*)(ws + 20480);            // 1024*5 f32  (pad 20480)
  ushort* w_ihb = (ushort*)(ws + 40960);           // 512*384 bf16 (393216 B)
  ushort* seq   = (ushort*)(ws + 40960 + 393216);  // 5120*384 bf16
  float*  G     = (float*)(ws + 40960 + 393216 +
                   (size_t)N_SAMP * NHIST * C_TRUNK * sizeof(ushort));

  argmax_kernel<<<N_SAMP, 320, 0, stream>>>(inp, w_ih, idxb, movb, w_ihb);
  gather_kernel<<<N_SAMP, 192, 0, stream>>>(trunk, idxb, movb, seq);
  gates_kernel<<<dim3(NGATE / 64, (N_SAMP * NHIST) / 64), 256, 0, stream>>>(
      seq, w_ihb, b_ih, b_hh, G);
  lstm_kernel<<<N_SAMP / 4, 512, 0, stream>>>(G, w_hh, w_proj, b_proj, out);
}